// Round 1
// baseline (3126.286 us; speedup 1.0000x reference)
//
#include <hip/hip_runtime.h>
#include <cstddef>

// SNN: 4-layer LIF net, T=200 sequential steps, batch 4096.
// Strategy: one workgroup (1024 thr / 16 waves) owns 16 batch rows for ALL
// 200 steps. Membranes in registers; spikes via LDS; weights as fp16 hi/lo
// split (lo pre-scaled x2048) streamed from L2; MFMA 16x16x32 f16 with fp32
// accumulate gives fp32-class numerics (spikes are exact in fp16).
//
// ws layout (in _Float16 units):
//   W1hi[256*96] W1lo[256*96] W2hi[256*256] W2lo[..] W3hi[..] W3lo[..]
//   total 311,296 halves = 622,592 bytes.

#define BATCH 4096
#define TSTEPS 200
#define NIN 80
#define KP 96        // layer-1 K padded to 3 k-tiles of 32
#define NH 256
#define XPAD 104     // x A-tile LDS row stride (halves); 104*2B=208B -> 2-way banks
#define SPAD 264     // spike LDS row stride (halves); 528B rows

#define W1HI 0
#define W1LO 24576
#define W2HI 49152
#define W2LO 114688
#define W3HI 180224
#define W3LO 245760

#define LO_SCALE 2048.0f          // keeps lo plane in fp16 normal range
#define LO_INV 4.8828125e-4f      // exact 2^-11

typedef _Float16 h8 __attribute__((ext_vector_type(8)));
typedef float f4 __attribute__((ext_vector_type(4)));

__global__ __launch_bounds__(256) void prep_kernel(
    const float* __restrict__ W1, const float* __restrict__ W2,
    const float* __restrict__ W3, _Float16* __restrict__ ws) {
  unsigned id = blockIdx.x * 256u + threadIdx.x;
  if (id >= 24576u + 65536u + 65536u) return;
  float v;
  unsigned off;
  _Float16 *hi, *lo;
  if (id < 24576u) {                       // W1: [256][80] -> padded [256][96]
    unsigned n = id / KP, k = id % KP;
    v = (k < NIN) ? W1[n * NIN + k] : 0.0f;
    hi = ws + W1HI; lo = ws + W1LO; off = id;
  } else if (id < 90112u) {                // W2: [256][256]
    off = id - 24576u; v = W2[off];
    hi = ws + W2HI; lo = ws + W2LO;
  } else {                                 // W3: [256][256]
    off = id - 90112u; v = W3[off];
    hi = ws + W3HI; lo = ws + W3LO;
  }
  _Float16 h = (_Float16)v;
  float r = (v - (float)h) * LO_SCALE;     // residual exact in fp32, scaled
  hi[off] = h;
  lo[off] = (_Float16)r;
}

__global__ __launch_bounds__(1024) void snn_kernel(
    const float* __restrict__ x,
    const float* __restrict__ b1, const float* __restrict__ b2,
    const float* __restrict__ b3, const float* __restrict__ W4,
    const float* __restrict__ b4, const _Float16* __restrict__ ws,
    float* __restrict__ out) {
  // LDS: ~52 KB total
  __shared__ alignas(16) _Float16 xAhi[4][16][XPAD];
  __shared__ alignas(16) _Float16 xAlo[4][16][XPAD];
  __shared__ alignas(16) _Float16 S1[16][SPAD];
  __shared__ alignas(16) _Float16 S2[16][SPAD];
  __shared__ alignas(16) _Float16 S3[16][SPAD];

  const int tid = threadIdx.x;
  const int wave = tid >> 6;        // 0..15 : 16-neuron slice / L4 batch row
  const int lane = tid & 63;
  const int n16 = lane & 15;        // MFMA: A-row (=batch m) & B-col (=neuron)
  const int kg = lane >> 4;         // k-group within fragment
  const int wb = blockIdx.x << 4;   // batch tile base
  const int nb = wave << 4;         // neuron slice base
  const int nn = nb + n16;          // this lane's output neuron (layers 1-3)

  const _Float16* w1h = ws + W1HI + nn * KP;
  const _Float16* w1l = ws + W1LO + nn * KP;
  const _Float16* w2h = ws + W2HI + nn * NH;
  const _Float16* w2l = ws + W2LO + nn * NH;
  const _Float16* w3h = ws + W3HI + nn * NH;
  const _Float16* w3l = ws + W3LO + nn * NH;

  const float bb1 = b1[nn], bb2 = b2[nn], bb3 = b3[nn];

  // Layer 4: wave handles batch row (wb+wave); half-wave per output j.
  const int j4 = lane >> 5;             // 0..1
  const int ks4 = (lane & 31) << 3;     // 8-wide k chunk
  float w4r[8];
#pragma unroll
  for (int u = 0; u < 8; ++u) w4r[u] = W4[j4 * NH + ks4 + u];
  const float bb4 = b4[j4];

  // Membranes: lane owns (m = kg*4+r, n = nn) per MFMA C/D layout.
  float mem1[4] = {0.f, 0.f, 0.f, 0.f};
  float mem2[4] = {0.f, 0.f, 0.f, 0.f};
  float mem3[4] = {0.f, 0.f, 0.f, 0.f};
  float mem4 = 0.f;

  for (int t = 0; t < TSTEPS; ++t) {
    const int ph = t & 3;
    if (ph == 0) {
      // Stage x[wb..wb+15][0..79][t..t+3] -> hi/lo fp16 A-tiles (float4 on t)
      for (unsigned e = (unsigned)tid; e < 16u * KP; e += 1024u) {
        unsigned m = e / KP, i = e % KP;
        f4 v = {0.f, 0.f, 0.f, 0.f};
        if (i < NIN)
          v = *(const f4*)(x + ((size_t)(wb + m) * NIN + i) * TSTEPS + t);
#pragma unroll
        for (int s = 0; s < 4; ++s) {
          float f = v[s];
          _Float16 h = (_Float16)f;
          xAhi[s][m][i] = h;
          xAlo[s][m][i] = (_Float16)((f - (float)h) * LO_SCALE);
        }
      }
      __syncthreads();
    }

    // ---------------- layer 1 : cur = x @ W1^T + b1 ----------------
    f4 aH = {0.f, 0.f, 0.f, 0.f};
    f4 aL = {0.f, 0.f, 0.f, 0.f};
#pragma unroll
    for (int kt = 0; kt < 3; ++kt) {
      const int ko = kt * 32 + kg * 8;
      h8 ahi = *(const h8*)&xAhi[ph][n16][ko];
      h8 alo = *(const h8*)&xAlo[ph][n16][ko];
      h8 whi = *(const h8*)(w1h + ko);
      h8 wlo = *(const h8*)(w1l + ko);
      aH = __builtin_amdgcn_mfma_f32_16x16x32_f16(ahi, whi, aH, 0, 0, 0);
      aL = __builtin_amdgcn_mfma_f32_16x16x32_f16(alo, whi, aL, 0, 0, 0);
      aL = __builtin_amdgcn_mfma_f32_16x16x32_f16(ahi, wlo, aL, 0, 0, 0);
    }
#pragma unroll
    for (int r = 0; r < 4; ++r) {
      float cur = __fadd_rn(__fadd_rn(aH[r], __fmul_rn(aL[r], LO_INV)), bb1);
      float mo = mem1[r];
      float mn = __fsub_rn(__fadd_rn(__fmul_rn(0.95f, mo), cur),
                           (mo > 1.0f) ? 1.0f : 0.0f);
      mem1[r] = mn;
      S1[kg * 4 + r][nn] = (mn > 1.0f) ? (_Float16)1.0f : (_Float16)0.0f;
    }
    __syncthreads();

    // ---------------- layer 2 : cur = s1 @ W2^T + b2 ----------------
    aH = (f4){0.f, 0.f, 0.f, 0.f};
    aL = (f4){0.f, 0.f, 0.f, 0.f};
#pragma unroll
    for (int kt = 0; kt < 8; ++kt) {
      const int ko = kt * 32 + kg * 8;
      h8 a = *(const h8*)&S1[n16][ko];
      h8 whi = *(const h8*)(w2h + ko);
      h8 wlo = *(const h8*)(w2l + ko);
      aH = __builtin_amdgcn_mfma_f32_16x16x32_f16(a, whi, aH, 0, 0, 0);
      aL = __builtin_amdgcn_mfma_f32_16x16x32_f16(a, wlo, aL, 0, 0, 0);
    }
#pragma unroll
    for (int r = 0; r < 4; ++r) {
      float cur = __fadd_rn(__fadd_rn(aH[r], __fmul_rn(aL[r], LO_INV)), bb2);
      float mo = mem2[r];
      float mn = __fsub_rn(__fadd_rn(__fmul_rn(0.95f, mo), cur),
                           (mo > 1.0f) ? 1.0f : 0.0f);
      mem2[r] = mn;
      S2[kg * 4 + r][nn] = (mn > 1.0f) ? (_Float16)1.0f : (_Float16)0.0f;
    }
    __syncthreads();

    // ---------------- layer 3 : cur = s2 @ W3^T + b3 ----------------
    aH = (f4){0.f, 0.f, 0.f, 0.f};
    aL = (f4){0.f, 0.f, 0.f, 0.f};
#pragma unroll
    for (int kt = 0; kt < 8; ++kt) {
      const int ko = kt * 32 + kg * 8;
      h8 a = *(const h8*)&S2[n16][ko];
      h8 whi = *(const h8*)(w3h + ko);
      h8 wlo = *(const h8*)(w3l + ko);
      aH = __builtin_amdgcn_mfma_f32_16x16x32_f16(a, whi, aH, 0, 0, 0);
      aL = __builtin_amdgcn_mfma_f32_16x16x32_f16(a, wlo, aL, 0, 0, 0);
    }
#pragma unroll
    for (int r = 0; r < 4; ++r) {
      float cur = __fadd_rn(__fadd_rn(aH[r], __fmul_rn(aL[r], LO_INV)), bb3);
      float mo = mem3[r];
      float mn = __fsub_rn(__fadd_rn(__fmul_rn(0.95f, mo), cur),
                           (mo > 1.0f) ? 1.0f : 0.0f);
      mem3[r] = mn;
      S3[kg * 4 + r][nn] = (mn > 1.0f) ? (_Float16)1.0f : (_Float16)0.0f;
    }
    __syncthreads();

    // ---------------- layer 4 : cur = s3 @ W4^T + b4 (VALU) ----------------
    {
      h8 s = *(const h8*)&S3[wave][ks4];
      float p = 0.0f;
#pragma unroll
      for (int u = 0; u < 8; ++u)
        p = __fadd_rn(p, __fmul_rn((float)s[u], w4r[u]));
#pragma unroll
      for (int msk = 1; msk <= 16; msk <<= 1)
        p = __fadd_rn(p, __shfl_xor(p, msk));
      float cur = __fadd_rn(p, bb4);
      float mo = mem4;
      float mn = __fsub_rn(__fadd_rn(__fmul_rn(0.95f, mo), cur),
                           (mo > 1.0f) ? 1.0f : 0.0f);
      mem4 = mn;
      if ((lane & 31) == 0)
        out[(size_t)t * (BATCH * 2) + (size_t)(wb + wave) * 2 + j4] =
            (mn > 1.0f) ? 1.0f : 0.0f;
    }
    // No trailing barrier needed: next step's first LDS write (S1) happens
    // after sync(S1-barrier of t+1), and S-buffer readers of step t are all
    // past earlier collective barriers. (t%4==0 restage is also safe: xA
    // readers finished before the S1 barrier of the previous step.)
  }
}

extern "C" void kernel_launch(void* const* d_in, const int* in_sizes, int n_in,
                              void* d_out, int out_size, void* d_ws,
                              size_t ws_size, hipStream_t stream) {
  const float* x  = (const float*)d_in[0];
  const float* W1 = (const float*)d_in[1];
  const float* b1 = (const float*)d_in[2];
  const float* W2 = (const float*)d_in[3];
  const float* b2 = (const float*)d_in[4];
  const float* W3 = (const float*)d_in[5];
  const float* b3 = (const float*)d_in[6];
  const float* W4 = (const float*)d_in[7];
  const float* b4 = (const float*)d_in[8];
  float* out = (float*)d_out;
  _Float16* ws = (_Float16*)d_ws;   // needs 622,592 B

  hipLaunchKernelGGL(prep_kernel, dim3(608), dim3(256), 0, stream,
                     W1, W2, W3, ws);
  hipLaunchKernelGGL(snn_kernel, dim3(BATCH / 16), dim3(1024), 0, stream,
                     x, b1, b2, b3, W4, b4, ws, out);
}

// Round 2
// 3008.669 us; speedup vs baseline: 1.0391x; 1.0391x over previous
//
#include <hip/hip_runtime.h>
#include <cstddef>

// SNN: 4-layer LIF net, T=200 sequential steps, batch 4096.
// R2: register-resident hi-planes of W2/W3 (loop-invariant, 64 VGPRs/lane),
// streamed lo-planes + W1 with grouped early issue, and raw LDS-only
// barriers (waitcnt lgkmcnt(0) + s_barrier) so global weight loads stay in
// flight across barriers. Numerics bitwise-identical to R1 (absmax 0):
// per-accumulator MFMA order unchanged.
//
// ws layout (_Float16 units): W1hi[256*96] W1lo[256*96] W2hi[256*256]
// W2lo[..] W3hi[..] W3lo[..]  -> 622,592 bytes.

#define BATCH 4096
#define TSTEPS 200
#define NIN 80
#define KP 96
#define NH 256
#define XPAD 104
#define SPAD 264

#define W1HI 0
#define W1LO 24576
#define W2HI 49152
#define W2LO 114688
#define W3HI 180224
#define W3LO 245760

#define LO_SCALE 2048.0f
#define LO_INV 4.8828125e-4f

typedef _Float16 h8 __attribute__((ext_vector_type(8)));
typedef float f4 __attribute__((ext_vector_type(4)));

// LDS-only barrier: wait lgkmcnt(0) (LDS writes visible), do NOT drain vmcnt.
// simm16: vmcnt[3:0]=15,[15:14]=3 (=63, no wait), expcnt=7, lgkmcnt=0 -> 0xC07F
__device__ __forceinline__ void lds_barrier() {
  __builtin_amdgcn_s_waitcnt(0xC07F);
  __builtin_amdgcn_s_barrier();
}

__global__ __launch_bounds__(256) void prep_kernel(
    const float* __restrict__ W1, const float* __restrict__ W2,
    const float* __restrict__ W3, _Float16* __restrict__ ws) {
  unsigned id = blockIdx.x * 256u + threadIdx.x;
  if (id >= 24576u + 65536u + 65536u) return;
  float v;
  unsigned off;
  _Float16 *hi, *lo;
  if (id < 24576u) {
    unsigned n = id / KP, k = id % KP;
    v = (k < NIN) ? W1[n * NIN + k] : 0.0f;
    hi = ws + W1HI; lo = ws + W1LO; off = id;
  } else if (id < 90112u) {
    off = id - 24576u; v = W2[off];
    hi = ws + W2HI; lo = ws + W2LO;
  } else {
    off = id - 90112u; v = W3[off];
    hi = ws + W3HI; lo = ws + W3LO;
  }
  _Float16 h = (_Float16)v;
  float r = (v - (float)h) * LO_SCALE;
  hi[off] = h;
  lo[off] = (_Float16)r;
}

__global__ __launch_bounds__(1024) void snn_kernel(
    const float* __restrict__ x,
    const float* __restrict__ b1, const float* __restrict__ b2,
    const float* __restrict__ b3, const float* __restrict__ W4,
    const float* __restrict__ b4, const _Float16* __restrict__ ws,
    float* __restrict__ out) {
  __shared__ alignas(16) _Float16 xAhi[4][16][XPAD];
  __shared__ alignas(16) _Float16 xAlo[4][16][XPAD];
  __shared__ alignas(16) _Float16 S1[16][SPAD];
  __shared__ alignas(16) _Float16 S2[16][SPAD];
  __shared__ alignas(16) _Float16 S3[16][SPAD];

  const int tid = threadIdx.x;
  const int wave = tid >> 6;
  const int lane = tid & 63;
  const int n16 = lane & 15;
  const int kg = lane >> 4;
  const int wb = blockIdx.x << 4;
  const int nn = (wave << 4) + n16;

  const _Float16* w1h = ws + W1HI + nn * KP;
  const _Float16* w1l = ws + W1LO + nn * KP;
  const _Float16* w2l = ws + W2LO + nn * NH;
  const _Float16* w3l = ws + W3LO + nn * NH;

  const float bb1 = b1[nn], bb2 = b2[nn], bb3 = b3[nn];

  // Loop-invariant hi-plane fragments for W2/W3: 2*8*4 = 64 VGPRs resident.
  h8 w2hi_r[8], w3hi_r[8];
  {
    const _Float16* w2h = ws + W2HI + nn * NH;
    const _Float16* w3h = ws + W3HI + nn * NH;
#pragma unroll
    for (int kt = 0; kt < 8; ++kt) {
      w2hi_r[kt] = *(const h8*)(w2h + kt * 32 + kg * 8);
      w3hi_r[kt] = *(const h8*)(w3h + kt * 32 + kg * 8);
    }
  }

  // Layer 4: wave handles batch row (wb+wave); half-wave per output j.
  const int j4 = lane >> 5;
  const int ks4 = (lane & 31) << 3;
  float w4r[8];
#pragma unroll
  for (int u = 0; u < 8; ++u) w4r[u] = W4[j4 * NH + ks4 + u];
  const float bb4 = b4[j4];

  float mem1[4] = {0.f, 0.f, 0.f, 0.f};
  float mem2[4] = {0.f, 0.f, 0.f, 0.f};
  float mem3[4] = {0.f, 0.f, 0.f, 0.f};
  float mem4 = 0.f;

  for (int t = 0; t < TSTEPS; ++t) {
    const int ph = t & 3;
    if (ph == 0) {
      for (unsigned e = (unsigned)tid; e < 16u * KP; e += 1024u) {
        unsigned m = e / KP, i = e % KP;
        f4 v = {0.f, 0.f, 0.f, 0.f};
        if (i < NIN)
          v = *(const f4*)(x + ((size_t)(wb + m) * NIN + i) * TSTEPS + t);
#pragma unroll
        for (int s = 0; s < 4; ++s) {
          float f = v[s];
          _Float16 h = (_Float16)f;
          xAhi[s][m][i] = h;
          xAlo[s][m][i] = (_Float16)((f - (float)h) * LO_SCALE);
        }
      }
      lds_barrier();
    }

    // ---------------- layer 1 : cur = x @ W1^T + b1 (streamed) -------------
    f4 aH = {0.f, 0.f, 0.f, 0.f};
    f4 aL = {0.f, 0.f, 0.f, 0.f};
    {
      h8 wh[3], wl[3];
#pragma unroll
      for (int kt = 0; kt < 3; ++kt) {
        wh[kt] = *(const h8*)(w1h + kt * 32 + kg * 8);
        wl[kt] = *(const h8*)(w1l + kt * 32 + kg * 8);
      }
#pragma unroll
      for (int kt = 0; kt < 3; ++kt) {
        const int ko = kt * 32 + kg * 8;
        h8 ahi = *(const h8*)&xAhi[ph][n16][ko];
        h8 alo = *(const h8*)&xAlo[ph][n16][ko];
        aH = __builtin_amdgcn_mfma_f32_16x16x32_f16(ahi, wh[kt], aH, 0, 0, 0);
        aL = __builtin_amdgcn_mfma_f32_16x16x32_f16(alo, wh[kt], aL, 0, 0, 0);
        aL = __builtin_amdgcn_mfma_f32_16x16x32_f16(ahi, wl[kt], aL, 0, 0, 0);
      }
    }
#pragma unroll
    for (int r = 0; r < 4; ++r) {
      float cur = __fadd_rn(__fadd_rn(aH[r], __fmul_rn(aL[r], LO_INV)), bb1);
      float mo = mem1[r];
      float mn = __fsub_rn(__fadd_rn(__fmul_rn(0.95f, mo), cur),
                           (mo > 1.0f) ? 1.0f : 0.0f);
      mem1[r] = mn;
      S1[kg * 4 + r][nn] = (mn > 1.0f) ? (_Float16)1.0f : (_Float16)0.0f;
    }
    lds_barrier();

    // ---------------- layer 2 : hi resident, lo streamed -------------------
    aH = (f4){0.f, 0.f, 0.f, 0.f};
    aL = (f4){0.f, 0.f, 0.f, 0.f};
#pragma unroll
    for (int g = 0; g < 2; ++g) {
      h8 wl[4];
#pragma unroll
      for (int q = 0; q < 4; ++q)
        wl[q] = *(const h8*)(w2l + (g * 4 + q) * 32 + kg * 8);
#pragma unroll
      for (int q = 0; q < 4; ++q) {
        const int kt = g * 4 + q;
        h8 a = *(const h8*)&S1[n16][kt * 32 + kg * 8];
        aH = __builtin_amdgcn_mfma_f32_16x16x32_f16(a, w2hi_r[kt], aH, 0, 0, 0);
        aL = __builtin_amdgcn_mfma_f32_16x16x32_f16(a, wl[q], aL, 0, 0, 0);
      }
    }
#pragma unroll
    for (int r = 0; r < 4; ++r) {
      float cur = __fadd_rn(__fadd_rn(aH[r], __fmul_rn(aL[r], LO_INV)), bb2);
      float mo = mem2[r];
      float mn = __fsub_rn(__fadd_rn(__fmul_rn(0.95f, mo), cur),
                           (mo > 1.0f) ? 1.0f : 0.0f);
      mem2[r] = mn;
      S2[kg * 4 + r][nn] = (mn > 1.0f) ? (_Float16)1.0f : (_Float16)0.0f;
    }
    lds_barrier();

    // ---------------- layer 3 : hi resident, lo streamed -------------------
    aH = (f4){0.f, 0.f, 0.f, 0.f};
    aL = (f4){0.f, 0.f, 0.f, 0.f};
#pragma unroll
    for (int g = 0; g < 2; ++g) {
      h8 wl[4];
#pragma unroll
      for (int q = 0; q < 4; ++q)
        wl[q] = *(const h8*)(w3l + (g * 4 + q) * 32 + kg * 8);
#pragma unroll
      for (int q = 0; q < 4; ++q) {
        const int kt = g * 4 + q;
        h8 a = *(const h8*)&S2[n16][kt * 32 + kg * 8];
        aH = __builtin_amdgcn_mfma_f32_16x16x32_f16(a, w3hi_r[kt], aH, 0, 0, 0);
        aL = __builtin_amdgcn_mfma_f32_16x16x32_f16(a, wl[q], aL, 0, 0, 0);
      }
    }
#pragma unroll
    for (int r = 0; r < 4; ++r) {
      float cur = __fadd_rn(__fadd_rn(aH[r], __fmul_rn(aL[r], LO_INV)), bb3);
      float mo = mem3[r];
      float mn = __fsub_rn(__fadd_rn(__fmul_rn(0.95f, mo), cur),
                           (mo > 1.0f) ? 1.0f : 0.0f);
      mem3[r] = mn;
      S3[kg * 4 + r][nn] = (mn > 1.0f) ? (_Float16)1.0f : (_Float16)0.0f;
    }
    lds_barrier();

    // ---------------- layer 4 : VALU dot + butterfly -----------------------
    {
      h8 s = *(const h8*)&S3[wave][ks4];
      float p = 0.0f;
#pragma unroll
      for (int u = 0; u < 8; ++u)
        p = __fadd_rn(p, __fmul_rn((float)s[u], w4r[u]));
#pragma unroll
      for (int msk = 1; msk <= 16; msk <<= 1)
        p = __fadd_rn(p, __shfl_xor(p, msk));
      float cur = __fadd_rn(p, bb4);
      float mo = mem4;
      float mn = __fsub_rn(__fadd_rn(__fmul_rn(0.95f, mo), cur),
                           (mo > 1.0f) ? 1.0f : 0.0f);
      mem4 = mn;
      if ((lane & 31) == 0)
        out[(size_t)t * (BATCH * 2) + (size_t)(wb + wave) * 2 + j4] =
            (mn > 1.0f) ? 1.0f : 0.0f;
    }
  }
}

extern "C" void kernel_launch(void* const* d_in, const int* in_sizes, int n_in,
                              void* d_out, int out_size, void* d_ws,
                              size_t ws_size, hipStream_t stream) {
  const float* x  = (const float*)d_in[0];
  const float* W1 = (const float*)d_in[1];
  const float* b1 = (const float*)d_in[2];
  const float* W2 = (const float*)d_in[3];
  const float* b2 = (const float*)d_in[4];
  const float* W3 = (const float*)d_in[5];
  const float* b3 = (const float*)d_in[6];
  const float* W4 = (const float*)d_in[7];
  const float* b4 = (const float*)d_in[8];
  float* out = (float*)d_out;
  _Float16* ws = (_Float16*)d_ws;

  hipLaunchKernelGGL(prep_kernel, dim3(608), dim3(256), 0, stream,
                     W1, W2, W3, ws);
  hipLaunchKernelGGL(snn_kernel, dim3(BATCH / 16), dim3(1024), 0, stream,
                     x, b1, b2, b3, W4, b4, ws, out);
}